// Round 10
// baseline (220.161 us; speedup 1.0000x reference)
//
#include <hip/hip_runtime.h>

typedef __bf16 bf16x8 __attribute__((ext_vector_type(8)));
typedef float f32x4 __attribute__((ext_vector_type(4)));
typedef __attribute__((address_space(1))) const unsigned char ga_t;
typedef __attribute__((address_space(3))) unsigned char la_t;

static __device__ __forceinline__ unsigned short f2b(float f) {
  union { float f; unsigned int i; } c; c.f = f;
  unsigned int r = c.i + 0x7FFFu + ((c.i >> 16) & 1u);
  return (unsigned short)(r >> 16);
}
// gfx950 HW packed f32->bf16 (RNE), low=a high=b
static __device__ __forceinline__ unsigned int pack2(float a, float b) {
  unsigned int r;
  asm("v_cvt_pk_bf16_f32 %0, %1, %2" : "=v"(r) : "v"(a), "v"(b));
  return r;
}
static __device__ __forceinline__ int4 ld8f_cvt(const float* __restrict__ p) {
  float4 a = *(const float4*)p;
  float4 b = *(const float4*)(p + 4);
  uint4 u;
  u.x = pack2(a.x, a.y); u.y = pack2(a.z, a.w);
  u.z = pack2(b.x, b.y); u.w = pack2(b.z, b.w);
  return *(int4*)&u;
}
static __device__ __forceinline__ void glds16(const unsigned short* g, unsigned short* l) {
  __builtin_amdgcn_global_load_lds((ga_t*)g, (la_t*)l, 16, 0, 0);
}

// fp32 -> bf16 convert, up to 4 streams via blockIdx.y
__global__ __launch_bounds__(256)
void cvt_z(const float* __restrict__ s0, const float* __restrict__ s1,
           const float* __restrict__ s2, const float* __restrict__ s3,
           unsigned short* d0, unsigned short* d1,
           unsigned short* d2, unsigned short* d3, int n8) {
  const int z = blockIdx.y;
  const float* s = z == 0 ? s0 : z == 1 ? s1 : z == 2 ? s2 : s3;
  unsigned short* d = z == 0 ? d0 : z == 1 ? d1 : z == 2 ? d2 : d3;
  int idx = blockIdx.x * 256 + threadIdx.x;
  if (idx < n8) *(int4*)(d + (size_t)idx * 8) = ld8f_cvt(s + (size_t)idx * 8);
}

// ---------------------------------------------------------------------------
// Shared GEMM core: 128x128 tile, BK=32, DOUBLE-BUFFERED glds staging
// (round-7 PASSING version, byte-verbatim). One barrier per K-step;
// staging hides under 16 MFMAs. LDS 32 KB.
// ---------------------------------------------------------------------------
static __device__ __forceinline__ void gemm_core(
    const unsigned short* __restrict__ A, const unsigned short* __restrict__ W,
    unsigned short* sA, unsigned short* sB, f32x4 acc[4][4],
    int K, int m0, int n0) {
  const int tid = threadIdx.x;
  const int wave = tid >> 6, lane = tid & 63, quad = lane >> 4, l16 = lane & 15;
  const int wrow = (wave >> 1) * 64, wcol = (wave & 1) * 64;
  const int r = tid >> 2, c8 = (tid & 3) * 8;

  const unsigned short* gA0 = A + (size_t)(m0 + r) * K + c8;
  const unsigned short* gA1 = gA0 + (size_t)64 * K;
  const unsigned short* gB0 = W + (size_t)(n0 + r) * K + c8;
  const unsigned short* gB1 = gB0 + (size_t)64 * K;
  unsigned short* lA0 = sA + tid * 8;   // buf1 adds 4096 shorts
  unsigned short* lA1 = lA0 + 2048;
  unsigned short* lB0 = sB + tid * 8;
  unsigned short* lB1 = lB0 + 2048;

  // prologue: tile 0 -> buf 0
  glds16(gA0, lA0);
  glds16(gA1, lA1);
  glds16(gB0, lB0);
  glds16(gB1, lB1);

  for (int k0 = 0; k0 < K; k0 += 32) {
    const int pb = (k0 >> 5) & 1;
    __syncthreads();  // tile k0 landed; buffer pb^1 free to overwrite

    // prefetch tile k0+32 into the other buffer (hidden under MFMAs)
    const int kn = (k0 + 32 < K) ? k0 + 32 : k0;
    const int nb = pb ^ 1;
    glds16(gA0 + kn, lA0 + nb * 4096);
    glds16(gA1 + kn, lA1 + nb * 4096);
    glds16(gB0 + kn, lB0 + nb * 4096);
    glds16(gB1 + kn, lB1 + nb * 4096);

    const unsigned short* cA = sA + pb * 4096;
    const unsigned short* cB = sB + pb * 4096;
    bf16x8 af[4], bfv[4];
#pragma unroll
    for (int i = 0; i < 4; ++i)
      af[i] = *(const bf16x8*)(&cA[(wrow + i * 16 + l16) * 32 + quad * 8]);
#pragma unroll
    for (int j = 0; j < 4; ++j)
      bfv[j] = *(const bf16x8*)(&cB[(wcol + j * 16 + l16) * 32 + quad * 8]);
#pragma unroll
    for (int i = 0; i < 4; ++i)
#pragma unroll
      for (int j = 0; j < 4; ++j)
        acc[i][j] = __builtin_amdgcn_mfma_f32_16x16x32_bf16(af[i], bfv[j], acc[i][j], 0, 0, 0);
  }
}

// QKV fused GEMM: z selects projection. z<2 -> bf16 C row-major (z==0 scaled
// by q0scale = log2(e)/sqrt(HD), folded softmax scale — Q only feeds attn);
// z==2 -> bf16 C^T (V transposed for attention), via per-wave LDS transpose.
__global__ __launch_bounds__(256, 3)
void gemm_qkv(const unsigned short* __restrict__ A0p, const unsigned short* __restrict__ A1p,
              const unsigned short* __restrict__ A2p,
              const unsigned short* __restrict__ W0p, const unsigned short* __restrict__ W1p,
              const unsigned short* __restrict__ W2p,
              const float* __restrict__ b0p, const float* __restrict__ b1p,
              const float* __restrict__ b2p,
              unsigned short* __restrict__ C0p, unsigned short* __restrict__ C1p,
              unsigned short* __restrict__ C2p,
              int M, int N, int K, int zbase, float q0scale) {
  __shared__ __align__(16) unsigned short smem[16384];  // sA[2] | sB[2], 32 KB
  const int z = blockIdx.z + zbase;
  const unsigned short* A = z == 0 ? A0p : z == 1 ? A1p : A2p;
  const unsigned short* W = z == 0 ? W0p : z == 1 ? W1p : W2p;
  const float* bias = z == 0 ? b0p : z == 1 ? b1p : b2p;

  const int tid = threadIdx.x;
  const int wave = tid >> 6, lane = tid & 63, quad = lane >> 4, l16 = lane & 15;
  const int m0 = blockIdx.x * 128, n0 = blockIdx.y * 128;
  const int wrow = (wave >> 1) * 64, wcol = (wave & 1) * 64;

  f32x4 acc[4][4];
#pragma unroll
  for (int i = 0; i < 4; ++i)
#pragma unroll
    for (int j = 0; j < 4; ++j) acc[i][j] = (f32x4){0.f, 0.f, 0.f, 0.f};

  gemm_core(A, W, smem, smem + 8192, acc, K, m0, n0);

  if (z < 2) {
    unsigned short* C = z == 0 ? C0p : C1p;
    const float qs = (z == 0) ? q0scale : 1.0f;
#pragma unroll
    for (int j = 0; j < 4; ++j) {
      const int col = n0 + wcol + j * 16 + l16;
      const float bv = bias[col];
#pragma unroll
      for (int i = 0; i < 4; ++i)
#pragma unroll
        for (int r = 0; r < 4; ++r) {
          const int row = m0 + wrow + i * 16 + quad * 4 + r;
          C[(size_t)row * N + col] = f2b((acc[i][j][r] + bv) * qs);
        }
    }
  } else {
    // transpose epilogue: reuse smem (per-wave 16x72 chunk), 4 passes of 16 cols
    __syncthreads();  // all waves done with frag reads (and last prefetch landed)
    unsigned short* sT = smem + wave * 1152;
#pragma unroll
    for (int j = 0; j < 4; ++j) {
      const float bv = bias[n0 + wcol + j * 16 + l16];
#pragma unroll
      for (int i = 0; i < 4; ++i) {
        uint2 pk;
        pk.x = pack2(acc[i][j][0] + bv, acc[i][j][1] + bv);
        pk.y = pack2(acc[i][j][2] + bv, acc[i][j][3] + bv);
        *(uint2*)(&sT[l16 * 72 + i * 16 + quad * 4]) = pk;
      }
      // same-wave LDS write->read (DS in-order within a wave)
#pragma unroll
      for (int t = 0; t < 2; ++t) {
        const int nl = lane >> 2;
        const int colh = (lane & 3) * 8 + t * 32;
        int4 v = *(const int4*)(&sT[nl * 72 + colh]);
        *(int4*)(&C2p[(size_t)(n0 + wcol + j * 16 + nl) * M + m0 + wrow + colh]) = v;
      }
    }
  }
}

// Output GEMM: bf16 A (attn out), bf16 W, fp32 C = d_out
__global__ __launch_bounds__(256, 3)
void gemm_out(const unsigned short* __restrict__ A, const unsigned short* __restrict__ W,
              const float* __restrict__ bias, float* __restrict__ C,
              int M, int N, int K) {
  __shared__ __align__(16) unsigned short smem[16384];
  const int tid = threadIdx.x;
  const int wave = tid >> 6, lane = tid & 63, quad = lane >> 4, l16 = lane & 15;
  const int m0 = blockIdx.x * 128, n0 = blockIdx.y * 128;
  const int wrow = (wave >> 1) * 64, wcol = (wave & 1) * 64;

  f32x4 acc[4][4];
#pragma unroll
  for (int i = 0; i < 4; ++i)
#pragma unroll
    for (int j = 0; j < 4; ++j) acc[i][j] = (f32x4){0.f, 0.f, 0.f, 0.f};

  gemm_core(A, W, smem, smem + 8192, acc, K, m0, n0);

#pragma unroll
  for (int j = 0; j < 4; ++j) {
    const int col = n0 + wcol + j * 16 + l16;
    const float bv = bias[col];
#pragma unroll
    for (int i = 0; i < 4; ++i)
#pragma unroll
      for (int r = 0; r < 4; ++r) {
        const int row = m0 + wrow + i * 16 + quad * 4 + r;
        C[(size_t)row * N + col] = acc[i][j][r] + bv;
      }
  }
}

// ---------------------------------------------------------------------------
// Fused attention: v12 BYTE-VERBATIM (the round-3/round-7 PASSING kernel).
// glds double-buffered K/V staging, stride-72 sP round-trip, setprio,
// bijective XCD swizzle. REPRODUCIBILITY ROUND: entire file is the exact
// round-7 source (passed at 219.09us). If this fails, the failure mechanism
// is runtime-nondeterministic (true race) and the structure gets rebuilt
// conservatively next round; if it passes, source-determinism is confirmed
// and round-9's failure is attributed to its gemm_out/epilogue changes.
// ---------------------------------------------------------------------------
#define SEQ 2048
#define DMODEL 1024

__global__ __launch_bounds__(256, 2)
void attn_fused(const unsigned short* __restrict__ Q,
                const unsigned short* __restrict__ Km,
                const unsigned short* __restrict__ Vt,   // [1024][4096]
                unsigned short* __restrict__ O) {
  __shared__ __align__(16) unsigned short sK[2][4096];   // [buf][(key16*2+half)*512 + lane*8]
  __shared__ __align__(16) unsigned short sVt[2][4096];  // [buf][(hg*2+half)*512 + lane*8]
  __shared__ __align__(16) unsigned short sPb[4][2304];  // per-wave 32 x 72

  const int tid = threadIdx.x;
  const int wave = tid >> 6, lane = tid & 63, quad = lane >> 4, l16 = lane & 15;

  // XCD-aware bijective swizzle: 512 blocks, 8 XCDs, contiguous 64-chunks.
  const int pid = blockIdx.y * gridDim.x + blockIdx.x;
  const int lid = (pid & 7) * 64 + (pid >> 3);
  const int qt = lid & 15;          // q-tile 0..15 (fast dim within an XCD)
  const int bh = lid >> 4;          // 0..31 (4 bh per XCD -> 2MB K/V, L2-res)
  const int b = bh >> 4, h = bh & 15;
  const size_t qrow0 = (size_t)b * SEQ + qt * 128;
  const size_t kvrow0 = (size_t)b * SEQ;
  const int hcol = h * 64;
  const int bofs = b * SEQ;
  const int qw = wave * 32;

  // Q fragments once, direct from global (pre-scaled by log2(e)/8)
  bf16x8 qa[2][2];
#pragma unroll
  for (int qi = 0; qi < 2; ++qi)
#pragma unroll
    for (int ks = 0; ks < 2; ++ks) {
      int4 v = *(const int4*)(&Q[(qrow0 + qw + qi * 16 + l16) * DMODEL + hcol + ks * 32 + quad * 8]);
      qa[qi][ks] = *(bf16x8*)&v;
    }

  // all-ones B fragment for the row-sum MFMA
  bf16x8 ones;
#pragma unroll
  for (int i = 0; i < 8; ++i) ones[i] = (__bf16)1.0f;

  unsigned short* sP = sPb[wave];

  f32x4 acc[2][4], lacc[2];
#pragma unroll
  for (int qi = 0; qi < 2; ++qi) {
    lacc[qi] = (f32x4){0.f, 0.f, 0.f, 0.f};
#pragma unroll
    for (int hg = 0; hg < 4; ++hg) acc[qi][hg] = (f32x4){0.f, 0.f, 0.f, 0.f};
  }

  // glds source/dest bases. Each wave DMAs key16-group `wave` of K and
  // hd16-group `wave` of V (2 halves each = 4 glds / wave / tile).
  const unsigned short* gK0 = Km + (kvrow0 + wave * 16 + l16) * DMODEL + hcol + quad * 8;
  const unsigned short* gV0 = Vt + (size_t)(hcol + wave * 16 + l16) * 4096 + bofs + quad * 8;
  unsigned short* lK0 = &sK[0][wave * 1024 + lane * 8];   // half adds 512
  unsigned short* lV0 = &sVt[0][wave * 1024 + lane * 8];

  // prologue: tile 0 -> buf 0
#pragma unroll
  for (int half = 0; half < 2; ++half) {
    glds16(gK0 + half * 32, lK0 + half * 512);
    glds16(gV0 + half * 32, lV0 + half * 512);
  }

  for (int kt = 0; kt < SEQ; kt += 64) {
    const int pb = (kt >> 6) & 1;
    __syncthreads();   // per-wave vmcnt(0) drain before s_barrier => tile kt landed

    // prefetch tile kt+64 into the other buffer (latency hidden under compute)
    const int ktn = (kt + 64 < SEQ) ? kt + 64 : kt;
    unsigned short* lKn = lK0 + (pb ^ 1) * 4096;
    unsigned short* lVn = lV0 + (pb ^ 1) * 4096;
#pragma unroll
    for (int half = 0; half < 2; ++half) {
      glds16(gK0 + (size_t)ktn * DMODEL + half * 32, lKn + half * 512);
      glds16(gV0 + ktn + half * 32, lVn + half * 512);
    }

    // S^T[key][q] = mfma(A=K frag, B=Q frag)
    f32x4 s[2][4];
#pragma unroll
    for (int qi = 0; qi < 2; ++qi)
#pragma unroll
      for (int kg = 0; kg < 4; ++kg) s[qi][kg] = (f32x4){0.f, 0.f, 0.f, 0.f};
    __builtin_amdgcn_s_setprio(1);
#pragma unroll
    for (int kg = 0; kg < 4; ++kg) {
      bf16x8 kb0 = *(const bf16x8*)(&sK[pb][(kg * 2 + 0) * 512 + lane * 8]);
      bf16x8 kb1 = *(const bf16x8*)(&sK[pb][(kg * 2 + 1) * 512 + lane * 8]);
#pragma unroll
      for (int qi = 0; qi < 2; ++qi) {
        s[qi][kg] = __builtin_amdgcn_mfma_f32_16x16x32_bf16(kb0, qa[qi][0], s[qi][kg], 0, 0, 0);
        s[qi][kg] = __builtin_amdgcn_mfma_f32_16x16x32_bf16(kb1, qa[qi][1], s[qi][kg], 0, 0, 0);
      }
    }
    __builtin_amdgcn_s_setprio(0);

    // exp2 (scale pre-folded), HW packed cvt -> b64 writes into q-major sP
#pragma unroll
    for (int qi = 0; qi < 2; ++qi)
#pragma unroll
      for (int kg = 0; kg < 4; ++kg) {
        float p0 = __builtin_amdgcn_exp2f(s[qi][kg][0]);
        float p1 = __builtin_amdgcn_exp2f(s[qi][kg][1]);
        float p2 = __builtin_amdgcn_exp2f(s[qi][kg][2]);
        float p3 = __builtin_amdgcn_exp2f(s[qi][kg][3]);
        uint2 pk; pk.x = pack2(p0, p1); pk.y = pack2(p2, p3);
        *(uint2*)(&sP[(qi * 16 + l16) * 72 + kg * 16 + quad * 4]) = pk;
      }

    // O += P V ; row-sums += P * ones  (same-wave LDS write->read, in-order)
#pragma unroll
    for (int ks = 0; ks < 2; ++ks) {
      bf16x8 pa[2], vb[4];
#pragma unroll
      for (int qi = 0; qi < 2; ++qi)
        pa[qi] = *(const bf16x8*)(&sP[(qi * 16 + l16) * 72 + ks * 32 + quad * 8]);
#pragma unroll
      for (int hg = 0; hg < 4; ++hg)
        vb[hg] = *(const bf16x8*)(&sVt[pb][(hg * 2 + ks) * 512 + lane * 8]);
      __builtin_amdgcn_s_setprio(1);
#pragma unroll
      for (int qi = 0; qi < 2; ++qi) {
#pragma unroll
        for (int hg = 0; hg < 4; ++hg)
          acc[qi][hg] = __builtin_amdgcn_mfma_f32_16x16x32_bf16(pa[qi], vb[hg], acc[qi][hg], 0, 0, 0);
        lacc[qi] = __builtin_amdgcn_mfma_f32_16x16x32_bf16(pa[qi], ones, lacc[qi], 0, 0, 0);
      }
      __builtin_amdgcn_s_setprio(0);
    }
  }

  // lacc[qi][r] = rowsum for row quad*4+r (same row the O-write uses)
#pragma unroll
  for (int qi = 0; qi < 2; ++qi)
#pragma unroll
    for (int r = 0; r < 4; ++r) {
      const float linv = 1.0f / lacc[qi][r];
      const size_t row = qrow0 + qw + qi * 16 + quad * 4 + r;
#pragma unroll
      for (int hg = 0; hg < 4; ++hg)
        O[row * DMODEL + hcol + hg * 16 + l16] = f2b(acc[qi][hg][r] * linv);
    }
}

// ---------------------------------------------------------------------------
extern "C" void kernel_launch(void* const* d_in, const int* in_sizes, int n_in,
                              void* d_out, int out_size, void* d_ws, size_t ws_size,
                              hipStream_t stream) {
  const float* xq = (const float*)d_in[0];
  const float* xv = (const float*)d_in[1];
  const float* xk = (const float*)d_in[2];
  const float* Wq = (const float*)d_in[3];
  const float* bq = (const float*)d_in[4];
  const float* Wk = (const float*)d_in[5];
  const float* bk = (const float*)d_in[6];
  const float* Wv = (const float*)d_in[7];
  const float* bv = (const float*)d_in[8];
  const float* Wo = (const float*)d_in[9];
  const float* bo = (const float*)d_in[10];
  float* out = (float*)d_out;

  const int S = 2048, D = 1024, M = 4096;
  const size_t MD = (size_t)M * D, DD = (size_t)D * D;
  const float SCL = 0.18033688011112042f;  // log2(e)/sqrt(64)
  unsigned short* P = (unsigned short*)d_ws;
  dim3 bb(256);
  dim3 gg(M / 128, D / 128);

  const size_t need = (3 * MD + 4 * DD + 3 * MD) * 2;
  if (ws_size >= need) {
    // fused path: all QKV in one z=3 launch (768 blocks = 3/CU)
    unsigned short* Ab = P;            // 3 act slices
    unsigned short* Wb = Ab + 3 * MD;  // 4 weight slices (q,k,v,o)
    unsigned short* Qw = Wb + 4 * DD;
    unsigned short* Kw = Qw + MD;
    unsigned short* Vtw = Kw + MD;
    unsigned short* Ao = Ab;           // attn out reuses act slice 0

    cvt_z<<<dim3((int)(MD / 8 / 256), 3), bb, 0, stream>>>(
        xq, xk, xv, xq, Ab, Ab + MD, Ab + 2 * MD, Ab, (int)(MD / 8));
    cvt_z<<<dim3((int)(DD / 8 / 256), 4), bb, 0, stream>>>(
        Wq, Wk, Wv, Wo, Wb, Wb + DD, Wb + 2 * DD, Wb + 3 * DD, (int)(DD / 8));
    gemm_qkv<<<dim3(M / 128, D / 128, 3), bb, 0, stream>>>(
        Ab, Ab + MD, Ab + 2 * MD, Wb, Wb + DD, Wb + 2 * DD,
        bq, bk, bv, Qw, Kw, Vtw, M, D, D, 0, SCL);
    attn_fused<<<dim3(S / 128, 32), bb, 0, stream>>>(Qw, Kw, Vtw, Ao);
    gemm_out<<<gg, bb, 0, stream>>>(Ao, Wb + 3 * DD, bo, out, M, D, D);
  } else {
    // sequential fallback (34 MB): act 8MB | W 2MB | Q 8 | K 8 | Vt 8
    unsigned short* Ab = P;
    unsigned short* Wb = Ab + MD;
    unsigned short* Qw = Wb + DD;
    unsigned short* Kw = Qw + MD;
    unsigned short* Vtw = Kw + MD;
    unsigned short* Ao = Ab;
    const int an = (int)(MD / 8), wn = (int)(DD / 8);

    cvt_z<<<dim3(an / 256, 1), bb, 0, stream>>>(xq, xq, xq, xq, Ab, Ab, Ab, Ab, an);
    cvt_z<<<dim3(wn / 256, 1), bb, 0, stream>>>(Wq, Wq, Wq, Wq, Wb, Wb, Wb, Wb, wn);
    gemm_qkv<<<dim3(M / 128, D / 128, 1), bb, 0, stream>>>(
        Ab, Ab, Ab, Wb, Wb, Wb, bq, bq, bq, Qw, Qw, Qw, M, D, D, 0, SCL);

    cvt_z<<<dim3(an / 256, 1), bb, 0, stream>>>(xk, xk, xk, xk, Ab, Ab, Ab, Ab, an);
    cvt_z<<<dim3(wn / 256, 1), bb, 0, stream>>>(Wk, Wk, Wk, Wk, Wb, Wb, Wb, Wb, wn);
    gemm_qkv<<<dim3(M / 128, D / 128, 1), bb, 0, stream>>>(
        Ab, Ab, Ab, Wb, Wb, Wb, bk, bk, bk, Kw, Kw, Kw, M, D, D, 0, 1.0f);

    cvt_z<<<dim3(an / 256, 1), bb, 0, stream>>>(xv, xv, xv, xv, Ab, Ab, Ab, Ab, an);
    cvt_z<<<dim3(wn / 256, 1), bb, 0, stream>>>(Wv, Wv, Wv, Wv, Wb, Wb, Wb, Wb, wn);
    gemm_qkv<<<dim3(M / 128, D / 128, 1), bb, 0, stream>>>(
        Ab, Ab, Ab, Wb, Wb, Wb, bv, bv, bv, Vtw, Vtw, Vtw, M, D, D, 2, 1.0f);

    attn_fused<<<dim3(S / 128, 32), bb, 0, stream>>>(Qw, Kw, Vtw, Ao);

    cvt_z<<<dim3(wn / 256, 1), bb, 0, stream>>>(Wo, Wo, Wo, Wo, Wb, Wb, Wb, Wb, wn);
    gemm_out<<<gg, bb, 0, stream>>>(Ao, Wb, bo, out, M, D, D);
  }
}

// Round 11
// 217.702 us; speedup vs baseline: 1.0113x; 1.0113x over previous
//
#include <hip/hip_runtime.h>

typedef __bf16 bf16x8 __attribute__((ext_vector_type(8)));
typedef float f32x4 __attribute__((ext_vector_type(4)));
typedef __attribute__((address_space(1))) const unsigned char ga_t;
typedef __attribute__((address_space(3))) unsigned char la_t;

static __device__ __forceinline__ unsigned short f2b(float f) {
  union { float f; unsigned int i; } c; c.f = f;
  unsigned int r = c.i + 0x7FFFu + ((c.i >> 16) & 1u);
  return (unsigned short)(r >> 16);
}
// gfx950 HW packed f32->bf16 (RNE), low=a high=b
static __device__ __forceinline__ unsigned int pack2(float a, float b) {
  unsigned int r;
  asm("v_cvt_pk_bf16_f32 %0, %1, %2" : "=v"(r) : "v"(a), "v"(b));
  return r;
}
static __device__ __forceinline__ int4 ld8f_cvt(const float* __restrict__ p) {
  float4 a = *(const float4*)p;
  float4 b = *(const float4*)(p + 4);
  uint4 u;
  u.x = pack2(a.x, a.y); u.y = pack2(a.z, a.w);
  u.z = pack2(b.x, b.y); u.w = pack2(b.z, b.w);
  return *(int4*)&u;
}
static __device__ __forceinline__ void glds16(const unsigned short* g, unsigned short* l) {
  __builtin_amdgcn_global_load_lds((ga_t*)g, (la_t*)l, 16, 0, 0);
}

// fp32 -> bf16 convert, up to 4 streams via blockIdx.y
__global__ __launch_bounds__(256)
void cvt_z(const float* __restrict__ s0, const float* __restrict__ s1,
           const float* __restrict__ s2, const float* __restrict__ s3,
           unsigned short* d0, unsigned short* d1,
           unsigned short* d2, unsigned short* d3, int n8) {
  const int z = blockIdx.y;
  const float* s = z == 0 ? s0 : z == 1 ? s1 : z == 2 ? s2 : s3;
  unsigned short* d = z == 0 ? d0 : z == 1 ? d1 : z == 2 ? d2 : d3;
  int idx = blockIdx.x * 256 + threadIdx.x;
  if (idx < n8) *(int4*)(d + (size_t)idx * 8) = ld8f_cvt(s + (size_t)idx * 8);
}

// ---------------------------------------------------------------------------
// Shared GEMM core: 128x128 tile, BK=32, DOUBLE-BUFFERED glds staging
// (round-7 PASSING version, byte-verbatim). One barrier per K-step;
// staging hides under 16 MFMAs. LDS 32 KB.
// ---------------------------------------------------------------------------
static __device__ __forceinline__ void gemm_core(
    const unsigned short* __restrict__ A, const unsigned short* __restrict__ W,
    unsigned short* sA, unsigned short* sB, f32x4 acc[4][4],
    int K, int m0, int n0) {
  const int tid = threadIdx.x;
  const int wave = tid >> 6, lane = tid & 63, quad = lane >> 4, l16 = lane & 15;
  const int wrow = (wave >> 1) * 64, wcol = (wave & 1) * 64;
  const int r = tid >> 2, c8 = (tid & 3) * 8;

  const unsigned short* gA0 = A + (size_t)(m0 + r) * K + c8;
  const unsigned short* gA1 = gA0 + (size_t)64 * K;
  const unsigned short* gB0 = W + (size_t)(n0 + r) * K + c8;
  const unsigned short* gB1 = gB0 + (size_t)64 * K;
  unsigned short* lA0 = sA + tid * 8;   // buf1 adds 4096 shorts
  unsigned short* lA1 = lA0 + 2048;
  unsigned short* lB0 = sB + tid * 8;
  unsigned short* lB1 = lB0 + 2048;

  // prologue: tile 0 -> buf 0
  glds16(gA0, lA0);
  glds16(gA1, lA1);
  glds16(gB0, lB0);
  glds16(gB1, lB1);

  for (int k0 = 0; k0 < K; k0 += 32) {
    const int pb = (k0 >> 5) & 1;
    __syncthreads();  // tile k0 landed; buffer pb^1 free to overwrite

    // prefetch tile k0+32 into the other buffer (hidden under MFMAs)
    const int kn = (k0 + 32 < K) ? k0 + 32 : k0;
    const int nb = pb ^ 1;
    glds16(gA0 + kn, lA0 + nb * 4096);
    glds16(gA1 + kn, lA1 + nb * 4096);
    glds16(gB0 + kn, lB0 + nb * 4096);
    glds16(gB1 + kn, lB1 + nb * 4096);

    const unsigned short* cA = sA + pb * 4096;
    const unsigned short* cB = sB + pb * 4096;
    bf16x8 af[4], bfv[4];
#pragma unroll
    for (int i = 0; i < 4; ++i)
      af[i] = *(const bf16x8*)(&cA[(wrow + i * 16 + l16) * 32 + quad * 8]);
#pragma unroll
    for (int j = 0; j < 4; ++j)
      bfv[j] = *(const bf16x8*)(&cB[(wcol + j * 16 + l16) * 32 + quad * 8]);
#pragma unroll
    for (int i = 0; i < 4; ++i)
#pragma unroll
      for (int j = 0; j < 4; ++j)
        acc[i][j] = __builtin_amdgcn_mfma_f32_16x16x32_bf16(af[i], bfv[j], acc[i][j], 0, 0, 0);
  }
}

// QKV fused GEMM: z selects projection. z<2 -> bf16 C row-major (z==0 scaled
// by q0scale = log2(e)/sqrt(HD), folded softmax scale — Q only feeds attn);
// z==2 -> bf16 C^T (V transposed for attention), via per-wave LDS transpose.
__global__ __launch_bounds__(256, 3)
void gemm_qkv(const unsigned short* __restrict__ A0p, const unsigned short* __restrict__ A1p,
              const unsigned short* __restrict__ A2p,
              const unsigned short* __restrict__ W0p, const unsigned short* __restrict__ W1p,
              const unsigned short* __restrict__ W2p,
              const float* __restrict__ b0p, const float* __restrict__ b1p,
              const float* __restrict__ b2p,
              unsigned short* __restrict__ C0p, unsigned short* __restrict__ C1p,
              unsigned short* __restrict__ C2p,
              int M, int N, int K, int zbase, float q0scale) {
  __shared__ __align__(16) unsigned short smem[16384];  // sA[2] | sB[2], 32 KB
  const int z = blockIdx.z + zbase;
  const unsigned short* A = z == 0 ? A0p : z == 1 ? A1p : A2p;
  const unsigned short* W = z == 0 ? W0p : z == 1 ? W1p : W2p;
  const float* bias = z == 0 ? b0p : z == 1 ? b1p : b2p;

  const int tid = threadIdx.x;
  const int wave = tid >> 6, lane = tid & 63, quad = lane >> 4, l16 = lane & 15;
  const int m0 = blockIdx.x * 128, n0 = blockIdx.y * 128;
  const int wrow = (wave >> 1) * 64, wcol = (wave & 1) * 64;

  f32x4 acc[4][4];
#pragma unroll
  for (int i = 0; i < 4; ++i)
#pragma unroll
    for (int j = 0; j < 4; ++j) acc[i][j] = (f32x4){0.f, 0.f, 0.f, 0.f};

  gemm_core(A, W, smem, smem + 8192, acc, K, m0, n0);

  if (z < 2) {
    unsigned short* C = z == 0 ? C0p : C1p;
    const float qs = (z == 0) ? q0scale : 1.0f;
#pragma unroll
    for (int j = 0; j < 4; ++j) {
      const int col = n0 + wcol + j * 16 + l16;
      const float bv = bias[col];
#pragma unroll
      for (int i = 0; i < 4; ++i)
#pragma unroll
        for (int r = 0; r < 4; ++r) {
          const int row = m0 + wrow + i * 16 + quad * 4 + r;
          C[(size_t)row * N + col] = f2b((acc[i][j][r] + bv) * qs);
        }
    }
  } else {
    // transpose epilogue: reuse smem (per-wave 16x72 chunk), 4 passes of 16 cols
    __syncthreads();  // all waves done with frag reads (and last prefetch landed)
    unsigned short* sT = smem + wave * 1152;
#pragma unroll
    for (int j = 0; j < 4; ++j) {
      const float bv = bias[n0 + wcol + j * 16 + l16];
#pragma unroll
      for (int i = 0; i < 4; ++i) {
        uint2 pk;
        pk.x = pack2(acc[i][j][0] + bv, acc[i][j][1] + bv);
        pk.y = pack2(acc[i][j][2] + bv, acc[i][j][3] + bv);
        *(uint2*)(&sT[l16 * 72 + i * 16 + quad * 4]) = pk;
      }
      // same-wave LDS write->read (DS in-order within a wave)
#pragma unroll
      for (int t = 0; t < 2; ++t) {
        const int nl = lane >> 2;
        const int colh = (lane & 3) * 8 + t * 32;
        int4 v = *(const int4*)(&sT[nl * 72 + colh]);
        *(int4*)(&C2p[(size_t)(n0 + wcol + j * 16 + nl) * M + m0 + wrow + colh]) = v;
      }
    }
  }
}

// ---------------------------------------------------------------------------
// Output GEMM v2: 64x128 tile (was 128x128 / 256 blocks = 1 block/CU, the
// worst occupancy in the pipeline). Grid 64x8 = 512 blocks = 2/CU; LDS 24 KB
// (sA 2x2048 + sB 2x4096 shorts); same proven dbuf-glds skeleton as
// gemm_core. A-row-sharing blocks are XCD-local (pid delta 64 == 0 mod 8).
// ISOLATED single delta vs round-10 source (attn/gemm_qkv/core untouched).
// ---------------------------------------------------------------------------
__global__ __launch_bounds__(256, 2)
void gemm_out(const unsigned short* __restrict__ A, const unsigned short* __restrict__ W,
              const float* __restrict__ bias, float* __restrict__ C,
              int M, int N, int K) {
  __shared__ __align__(16) unsigned short smem[12288];  // sA[2][2048] | sB[2][4096]
  const int tid = threadIdx.x;
  const int wave = tid >> 6, lane = tid & 63, quad = lane >> 4, l16 = lane & 15;
  const int m0 = blockIdx.x * 64, n0 = blockIdx.y * 128;
  const int wrow = (wave >> 1) * 32, wcol = (wave & 1) * 64;
  const int r = tid >> 2, c8 = (tid & 3) * 8;

  unsigned short* sA = smem;          // buf1 adds 2048 shorts
  unsigned short* sB = smem + 4096;   // buf1 adds 4096 shorts

  const unsigned short* gA0 = A + (size_t)(m0 + r) * K + c8;   // 64 rows x 32
  const unsigned short* gB0 = W + (size_t)(n0 + r) * K + c8;   // rows 0-63
  const unsigned short* gB1 = gB0 + (size_t)64 * K;            // rows 64-127
  unsigned short* lA0 = sA + tid * 8;
  unsigned short* lB0 = sB + tid * 8;
  unsigned short* lB1 = lB0 + 2048;

  f32x4 acc[2][4];
#pragma unroll
  for (int i = 0; i < 2; ++i)
#pragma unroll
    for (int j = 0; j < 4; ++j) acc[i][j] = (f32x4){0.f, 0.f, 0.f, 0.f};

  // prologue: tile 0 -> buf 0
  glds16(gA0, lA0);
  glds16(gB0, lB0);
  glds16(gB1, lB1);

  for (int k0 = 0; k0 < K; k0 += 32) {
    const int pb = (k0 >> 5) & 1;
    __syncthreads();  // tile k0 landed; buffer pb^1 free to overwrite

    const int kn = (k0 + 32 < K) ? k0 + 32 : k0;
    const int nb = pb ^ 1;
    glds16(gA0 + kn, lA0 + nb * 2048);
    glds16(gB0 + kn, lB0 + nb * 4096);
    glds16(gB1 + kn, lB1 + nb * 4096);

    const unsigned short* cA = sA + pb * 2048;
    const unsigned short* cB = sB + pb * 4096;
    bf16x8 af[2], bfv[4];
#pragma unroll
    for (int i = 0; i < 2; ++i)
      af[i] = *(const bf16x8*)(&cA[(wrow + i * 16 + l16) * 32 + quad * 8]);
#pragma unroll
    for (int j = 0; j < 4; ++j)
      bfv[j] = *(const bf16x8*)(&cB[(wcol + j * 16 + l16) * 32 + quad * 8]);
#pragma unroll
    for (int i = 0; i < 2; ++i)
#pragma unroll
      for (int j = 0; j < 4; ++j)
        acc[i][j] = __builtin_amdgcn_mfma_f32_16x16x32_bf16(af[i], bfv[j], acc[i][j], 0, 0, 0);
  }

#pragma unroll
  for (int j = 0; j < 4; ++j) {
    const int col = n0 + wcol + j * 16 + l16;
    const float bv = bias[col];
#pragma unroll
    for (int i = 0; i < 2; ++i)
#pragma unroll
      for (int rr = 0; rr < 4; ++rr) {
        const int row = m0 + wrow + i * 16 + quad * 4 + rr;
        C[(size_t)row * N + col] = acc[i][j][rr] + bv;
      }
  }
}

// ---------------------------------------------------------------------------
// Fused attention: v12 BYTE-VERBATIM (the round-3/7/10 PASSING kernel,
// 55.5us). FROZEN: every source edit to this kernel (6 attempts) flipped a
// schedule-sensitive razor edge (absmax ~0.06-0.08); per-function codegen
// isolation (r3->r7 gemm edit, attn unchanged -> PASS) makes sibling-kernel
// edits safe. Do not touch this function.
// ---------------------------------------------------------------------------
#define SEQ 2048
#define DMODEL 1024

__global__ __launch_bounds__(256, 2)
void attn_fused(const unsigned short* __restrict__ Q,
                const unsigned short* __restrict__ Km,
                const unsigned short* __restrict__ Vt,   // [1024][4096]
                unsigned short* __restrict__ O) {
  __shared__ __align__(16) unsigned short sK[2][4096];   // [buf][(key16*2+half)*512 + lane*8]
  __shared__ __align__(16) unsigned short sVt[2][4096];  // [buf][(hg*2+half)*512 + lane*8]
  __shared__ __align__(16) unsigned short sPb[4][2304];  // per-wave 32 x 72

  const int tid = threadIdx.x;
  const int wave = tid >> 6, lane = tid & 63, quad = lane >> 4, l16 = lane & 15;

  // XCD-aware bijective swizzle: 512 blocks, 8 XCDs, contiguous 64-chunks.
  const int pid = blockIdx.y * gridDim.x + blockIdx.x;
  const int lid = (pid & 7) * 64 + (pid >> 3);
  const int qt = lid & 15;          // q-tile 0..15 (fast dim within an XCD)
  const int bh = lid >> 4;          // 0..31 (4 bh per XCD -> 2MB K/V, L2-res)
  const int b = bh >> 4, h = bh & 15;
  const size_t qrow0 = (size_t)b * SEQ + qt * 128;
  const size_t kvrow0 = (size_t)b * SEQ;
  const int hcol = h * 64;
  const int bofs = b * SEQ;
  const int qw = wave * 32;

  // Q fragments once, direct from global (pre-scaled by log2(e)/8)
  bf16x8 qa[2][2];
#pragma unroll
  for (int qi = 0; qi < 2; ++qi)
#pragma unroll
    for (int ks = 0; ks < 2; ++ks) {
      int4 v = *(const int4*)(&Q[(qrow0 + qw + qi * 16 + l16) * DMODEL + hcol + ks * 32 + quad * 8]);
      qa[qi][ks] = *(bf16x8*)&v;
    }

  // all-ones B fragment for the row-sum MFMA
  bf16x8 ones;
#pragma unroll
  for (int i = 0; i < 8; ++i) ones[i] = (__bf16)1.0f;

  unsigned short* sP = sPb[wave];

  f32x4 acc[2][4], lacc[2];
#pragma unroll
  for (int qi = 0; qi < 2; ++qi) {
    lacc[qi] = (f32x4){0.f, 0.f, 0.f, 0.f};
#pragma unroll
    for (int hg = 0; hg < 4; ++hg) acc[qi][hg] = (f32x4){0.f, 0.f, 0.f, 0.f};
  }

  // glds source/dest bases. Each wave DMAs key16-group `wave` of K and
  // hd16-group `wave` of V (2 halves each = 4 glds / wave / tile).
  const unsigned short* gK0 = Km + (kvrow0 + wave * 16 + l16) * DMODEL + hcol + quad * 8;
  const unsigned short* gV0 = Vt + (size_t)(hcol + wave * 16 + l16) * 4096 + bofs + quad * 8;
  unsigned short* lK0 = &sK[0][wave * 1024 + lane * 8];   // half adds 512
  unsigned short* lV0 = &sVt[0][wave * 1024 + lane * 8];

  // prologue: tile 0 -> buf 0
#pragma unroll
  for (int half = 0; half < 2; ++half) {
    glds16(gK0 + half * 32, lK0 + half * 512);
    glds16(gV0 + half * 32, lV0 + half * 512);
  }

  for (int kt = 0; kt < SEQ; kt += 64) {
    const int pb = (kt >> 6) & 1;
    __syncthreads();   // per-wave vmcnt(0) drain before s_barrier => tile kt landed

    // prefetch tile kt+64 into the other buffer (latency hidden under compute)
    const int ktn = (kt + 64 < SEQ) ? kt + 64 : kt;
    unsigned short* lKn = lK0 + (pb ^ 1) * 4096;
    unsigned short* lVn = lV0 + (pb ^ 1) * 4096;
#pragma unroll
    for (int half = 0; half < 2; ++half) {
      glds16(gK0 + (size_t)ktn * DMODEL + half * 32, lKn + half * 512);
      glds16(gV0 + ktn + half * 32, lVn + half * 512);
    }

    // S^T[key][q] = mfma(A=K frag, B=Q frag)
    f32x4 s[2][4];
#pragma unroll
    for (int qi = 0; qi < 2; ++qi)
#pragma unroll
      for (int kg = 0; kg < 4; ++kg) s[qi][kg] = (f32x4){0.f, 0.f, 0.f, 0.f};
    __builtin_amdgcn_s_setprio(1);
#pragma unroll
    for (int kg = 0; kg < 4; ++kg) {
      bf16x8 kb0 = *(const bf16x8*)(&sK[pb][(kg * 2 + 0) * 512 + lane * 8]);
      bf16x8 kb1 = *(const bf16x8*)(&sK[pb][(kg * 2 + 1) * 512 + lane * 8]);
#pragma unroll
      for (int qi = 0; qi < 2; ++qi) {
        s[qi][kg] = __builtin_amdgcn_mfma_f32_16x16x32_bf16(kb0, qa[qi][0], s[qi][kg], 0, 0, 0);
        s[qi][kg] = __builtin_amdgcn_mfma_f32_16x16x32_bf16(kb1, qa[qi][1], s[qi][kg], 0, 0, 0);
      }
    }
    __builtin_amdgcn_s_setprio(0);

    // exp2 (scale pre-folded), HW packed cvt -> b64 writes into q-major sP
#pragma unroll
    for (int qi = 0; qi < 2; ++qi)
#pragma unroll
      for (int kg = 0; kg < 4; ++kg) {
        float p0 = __builtin_amdgcn_exp2f(s[qi][kg][0]);
        float p1 = __builtin_amdgcn_exp2f(s[qi][kg][1]);
        float p2 = __builtin_amdgcn_exp2f(s[qi][kg][2]);
        float p3 = __builtin_amdgcn_exp2f(s[qi][kg][3]);
        uint2 pk; pk.x = pack2(p0, p1); pk.y = pack2(p2, p3);
        *(uint2*)(&sP[(qi * 16 + l16) * 72 + kg * 16 + quad * 4]) = pk;
      }

    // O += P V ; row-sums += P * ones  (same-wave LDS write->read, in-order)
#pragma unroll
    for (int ks = 0; ks < 2; ++ks) {
      bf16x8 pa[2], vb[4];
#pragma unroll
      for (int qi = 0; qi < 2; ++qi)
        pa[qi] = *(const bf16x8*)(&sP[(qi * 16 + l16) * 72 + ks * 32 + quad * 8]);
#pragma unroll
      for (int hg = 0; hg < 4; ++hg)
        vb[hg] = *(const bf16x8*)(&sVt[pb][(hg * 2 + ks) * 512 + lane * 8]);
      __builtin_amdgcn_s_setprio(1);
#pragma unroll
      for (int qi = 0; qi < 2; ++qi) {
#pragma unroll
        for (int hg = 0; hg < 4; ++hg)
          acc[qi][hg] = __builtin_amdgcn_mfma_f32_16x16x32_bf16(pa[qi], vb[hg], acc[qi][hg], 0, 0, 0);
        lacc[qi] = __builtin_amdgcn_mfma_f32_16x16x32_bf16(pa[qi], ones, lacc[qi], 0, 0, 0);
      }
      __builtin_amdgcn_s_setprio(0);
    }
  }

  // lacc[qi][r] = rowsum for row quad*4+r (same row the O-write uses)
#pragma unroll
  for (int qi = 0; qi < 2; ++qi)
#pragma unroll
    for (int r = 0; r < 4; ++r) {
      const float linv = 1.0f / lacc[qi][r];
      const size_t row = qrow0 + qw + qi * 16 + quad * 4 + r;
#pragma unroll
      for (int hg = 0; hg < 4; ++hg)
        O[row * DMODEL + hcol + hg * 16 + l16] = f2b(acc[qi][hg][r] * linv);
    }
}

// ---------------------------------------------------------------------------
extern "C" void kernel_launch(void* const* d_in, const int* in_sizes, int n_in,
                              void* d_out, int out_size, void* d_ws, size_t ws_size,
                              hipStream_t stream) {
  const float* xq = (const float*)d_in[0];
  const float* xv = (const float*)d_in[1];
  const float* xk = (const float*)d_in[2];
  const float* Wq = (const float*)d_in[3];
  const float* bq = (const float*)d_in[4];
  const float* Wk = (const float*)d_in[5];
  const float* bk = (const float*)d_in[6];
  const float* Wv = (const float*)d_in[7];
  const float* bv = (const float*)d_in[8];
  const float* Wo = (const float*)d_in[9];
  const float* bo = (const float*)d_in[10];
  float* out = (float*)d_out;

  const int S = 2048, D = 1024, M = 4096;
  const size_t MD = (size_t)M * D, DD = (size_t)D * D;
  const float SCL = 0.18033688011112042f;  // log2(e)/sqrt(64)
  unsigned short* P = (unsigned short*)d_ws;
  dim3 bb(256);
  dim3 gg(M / 64, D / 128);   // gemm_out 64x128 tiles: 512 blocks = 2/CU

  const size_t need = (3 * MD + 4 * DD + 3 * MD) * 2;
  if (ws_size >= need) {
    // fused path: all QKV in one z=3 launch (768 blocks = 3/CU)
    unsigned short* Ab = P;            // 3 act slices
    unsigned short* Wb = Ab + 3 * MD;  // 4 weight slices (q,k,v,o)
    unsigned short* Qw = Wb + 4 * DD;
    unsigned short* Kw = Qw + MD;
    unsigned short* Vtw = Kw + MD;
    unsigned short* Ao = Ab;           // attn out reuses act slice 0

    cvt_z<<<dim3((int)(MD / 8 / 256), 3), bb, 0, stream>>>(
        xq, xk, xv, xq, Ab, Ab + MD, Ab + 2 * MD, Ab, (int)(MD / 8));
    cvt_z<<<dim3((int)(DD / 8 / 256), 4), bb, 0, stream>>>(
        Wq, Wk, Wv, Wo, Wb, Wb + DD, Wb + 2 * DD, Wb + 3 * DD, (int)(DD / 8));
    gemm_qkv<<<dim3(M / 128, D / 128, 3), bb, 0, stream>>>(
        Ab, Ab + MD, Ab + 2 * MD, Wb, Wb + DD, Wb + 2 * DD,
        bq, bk, bv, Qw, Kw, Vtw, M, D, D, 0, SCL);
    attn_fused<<<dim3(S / 128, 32), bb, 0, stream>>>(Qw, Kw, Vtw, Ao);
    gemm_out<<<gg, bb, 0, stream>>>(Ao, Wb + 3 * DD, bo, out, M, D, D);
  } else {
    // sequential fallback (34 MB): act 8MB | W 2MB | Q 8 | K 8 | Vt 8
    unsigned short* Ab = P;
    unsigned short* Wb = Ab + MD;
    unsigned short* Qw = Wb + DD;
    unsigned short* Kw = Qw + MD;
    unsigned short* Vtw = Kw + MD;
    unsigned short* Ao = Ab;
    const int an = (int)(MD / 8), wn = (int)(DD / 8);

    cvt_z<<<dim3(an / 256, 1), bb, 0, stream>>>(xq, xq, xq, xq, Ab, Ab, Ab, Ab, an);
    cvt_z<<<dim3(wn / 256, 1), bb, 0, stream>>>(Wq, Wq, Wq, Wq, Wb, Wb, Wb, Wb, wn);
    gemm_qkv<<<dim3(M / 128, D / 128, 1), bb, 0, stream>>>(
        Ab, Ab, Ab, Wb, Wb, Wb, bq, bq, bq, Qw, Qw, Qw, M, D, D, 0, SCL);

    cvt_z<<<dim3(an / 256, 1), bb, 0, stream>>>(xk, xk, xk, xk, Ab, Ab, Ab, Ab, an);
    cvt_z<<<dim3(wn / 256, 1), bb, 0, stream>>>(Wk, Wk, Wk, Wk, Wb, Wb, Wb, Wb, wn);
    gemm_qkv<<<dim3(M / 128, D / 128, 1), bb, 0, stream>>>(
        Ab, Ab, Ab, Wb, Wb, Wb, bk, bk, bk, Kw, Kw, Kw, M, D, D, 0, 1.0f);

    cvt_z<<<dim3(an / 256, 1), bb, 0, stream>>>(xv, xv, xv, xv, Ab, Ab, Ab, Ab, an);
    cvt_z<<<dim3(wn / 256, 1), bb, 0, stream>>>(Wv, Wv, Wv, Wv, Wb, Wb, Wb, Wb, wn);
    gemm_qkv<<<dim3(M / 128, D / 128, 1), bb, 0, stream>>>(
        Ab, Ab, Ab, Wb, Wb, Wb, bv, bv, bv, Vtw, Vtw, Vtw, M, D, D, 2, 1.0f);

    attn_fused<<<dim3(S / 128, 32), bb, 0, stream>>>(Qw, Kw, Vtw, Ao);

    cvt_z<<<dim3(wn / 256, 1), bb, 0, stream>>>(Wo, Wo, Wo, Wo, Wb, Wb, Wb, Wb, wn);
    gemm_out<<<gg, bb, 0, stream>>>(Ao, Wb, bo, out, M, D, D);
  }
}